// Round 6
// baseline (73.519 us; speedup 1.0000x reference)
//
#include <hip/hip_runtime.h>

typedef float f32x4 __attribute__((ext_vector_type(4)));
typedef _Float16 f16x8 __attribute__((ext_vector_type(8)));
typedef _Float16 f16x4 __attribute__((ext_vector_type(4)));
typedef int i32x4 __attribute__((ext_vector_type(4)));
typedef int i32x2 __attribute__((ext_vector_type(2)));

#define WAVES 4

__device__ __forceinline__ f32x4 mfma16(f16x8 a, f16x8 b, f32x4 c) {
    return __builtin_amdgcn_mfma_f32_16x16x32_f16(a, b, c, 0, 0, 0);
}

// 8 consecutive k-elements (fp32) -> fp16 fragment, RNE
__device__ __forceinline__ f16x8 cvt8(f32x4 a, f32x4 b) {
    f16x8 h;
#pragma unroll
    for (int j = 0; j < 4; ++j) { h[j] = (_Float16)a[j]; h[j + 4] = (_Float16)b[j]; }
    return h;
}

// relu + pack one accumulator quad (4 f32) -> 2 dwords of fp16 pairs
__device__ __forceinline__ i32x2 relu_pk2(f32x4 a) {
    f16x4 v;
#pragma unroll
    for (int j = 0; j < 4; ++j) v[j] = (_Float16)fmaxf(a[j], 0.0f);
    return __builtin_bit_cast(i32x2, v);
}

// B-fragment = concat of two packed quads -- pure register move.
__device__ __forceinline__ f16x8 cat(i32x2 a, i32x2 b) {
    i32x4 v; v[0] = a[0]; v[1] = a[1]; v[2] = b[0]; v[3] = b[1];
    return __builtin_bit_cast(f16x8, v);
}

// Orientation: D[m=neuron][n=batch]. mfma_f32_16x16x32_f16 layouts (HW-verified R1-R5):
//   A: lane l supplies A[l&15][8*(l>>4)+j]
//   B: lane l supplies B[8*(l>>4)+j][l&15]
//   D: lane l holds   D[4*(l>>4)+r][l&15]
// Hidden-neuron permutation phi(32s+8g+j) = 16*(2s+(j>>2)) + 4g + (j&3) makes each
// lane's next-layer B-fragment its own packed accumulators (zero cross-lane traffic);
// W1/W2 columns are loaded phi-gathered (two contiguous f32x4 loads per fragment).
//
// Memory structure: FOUR independent single-tile prefetch slots (round-robin,
// static register names -> no scratch), 8 KB in flight per wave; single-tile
// work granularity cuts the grid-stride tail imbalance from 4.8% to 1.6%.
// Nontemporal Y stores (streamed, never re-read; keeps L3 for X across replays).
__global__ __launch_bounds__(256, 4) void mlp_kernel(
    const float* __restrict__ X, const float* __restrict__ W0,
    const float* __restrict__ W1, const float* __restrict__ W2,
    float* __restrict__ Y, int ntiles)
{
    const int tid  = threadIdx.x;
    const int wid  = tid >> 6;
    const int lane = tid & 63;
    const int b16  = lane & 15;
    const int g    = lane >> 4;

    // ---- fp16 weight fragments (RNE), loaded once per wave ----
    f16x8 w0[4], w1[4][2], w2[2];
#pragma unroll
    for (int t = 0; t < 4; ++t) {
        const float* p = W0 + (16 * t + b16) * 32 + 8 * g;   // cols unpermuted (input dim)
        w0[t] = cvt8(*(const f32x4*)p, *(const f32x4*)(p + 4));
    }
#pragma unroll
    for (int t = 0; t < 4; ++t) {
#pragma unroll
        for (int s = 0; s < 2; ++s) {
            const float* p = W1 + (16 * t + b16) * 64 + 32 * s + 4 * g;  // phi-gathered
            w1[t][s] = cvt8(*(const f32x4*)p, *(const f32x4*)(p + 16));
        }
    }
#pragma unroll
    for (int s = 0; s < 2; ++s) {
        const float* p = W2 + b16 * 64 + 32 * s + 4 * g;                 // phi-gathered
        w2[s] = cvt8(*(const f32x4*)p, *(const f32x4*)(p + 16));
    }

    const int xoff = b16 * 32 + 8 * g;    // float offset within a 16x32 input tile
    const int yoff = b16 * 16 + 4 * g;    // float offset within a 16x16 output tile

    const int gwid = blockIdx.x * WAVES + wid;
    const int G    = gridDim.x * WAVES;
    if (gwid >= ntiles) return;

    // clamped tile load (OOB slots reload gwid's tile; result discarded/duplicated)
#define LOADT(d0, d1, t)                                                        \
    {                                                                           \
        const int tc = ((t) < ntiles) ? (t) : gwid;                             \
        const float* xp_ = X + (size_t)tc * 512 + xoff;                         \
        d0 = *(const f32x4*)xp_;  d1 = *(const f32x4*)(xp_ + 4);                \
    }

    // one 16-row tile: fp16 input fragment -> 16 outputs, nontemporal store
#define COMPUTE_STORE(xa, t)                                                    \
    {                                                                           \
        i32x2 pk[4];                                                            \
        _Pragma("unroll")                                                       \
        for (int q_ = 0; q_ < 4; ++q_) {                                        \
            f32x4 z = {0.f, 0.f, 0.f, 0.f};                                     \
            z = mfma16(w0[q_], xa, z);                                          \
            pk[q_] = relu_pk2(z);                                               \
        }                                                                       \
        f32x4 c[4];                                                             \
        _Pragma("unroll")                                                       \
        for (int q_ = 0; q_ < 4; ++q_) c[q_] = (f32x4){0.f, 0.f, 0.f, 0.f};     \
        const f16x8 f0 = cat(pk[0], pk[1]);                                     \
        _Pragma("unroll")                                                       \
        for (int q_ = 0; q_ < 4; ++q_) c[q_] = mfma16(w1[q_][0], f0, c[q_]);    \
        const f16x8 f1 = cat(pk[2], pk[3]);                                     \
        _Pragma("unroll")                                                       \
        for (int q_ = 0; q_ < 4; ++q_) c[q_] = mfma16(w1[q_][1], f1, c[q_]);    \
        i32x2 qq[4];                                                            \
        _Pragma("unroll")                                                       \
        for (int q_ = 0; q_ < 4; ++q_) qq[q_] = relu_pk2(c[q_]);                \
        f32x4 o = {0.f, 0.f, 0.f, 0.f};                                         \
        o = mfma16(w2[0], cat(qq[0], qq[1]), o);                                \
        o = mfma16(w2[1], cat(qq[2], qq[3]), o);                                \
        float* yp_ = Y + (size_t)(t) * 256 + yoff;                              \
        __builtin_nontemporal_store(o, (f32x4*)yp_);                            \
    }

    // phase: consume slot (tile t), refill slot for t+4G, compute+store, advance
#define PHASE(d0, d1, t)                                                        \
    {                                                                           \
        const f16x8 xa = cvt8(d0, d1);                                          \
        const int tn = (t) + 4 * G;                                             \
        LOADT(d0, d1, tn)                                                       \
        COMPUTE_STORE(xa, t)                                                    \
        t = tn;                                                                 \
    }

    int t0 = gwid, t1 = t0 + G, t2 = t1 + G, t3 = t2 + G;

    f32x4 a0, a1, b0, b1, c0, c1, d0, d1;   // 4 single-tile slots
    LOADT(a0, a1, t0)
    LOADT(b0, b1, t1)
    LOADT(c0, c1, t2)
    LOADT(d0, d1, t3)

    while (true) {
        PHASE(a0, a1, t0)
        if (t1 >= ntiles) break;
        PHASE(b0, b1, t1)
        if (t2 >= ntiles) break;
        PHASE(c0, c1, t2)
        if (t3 >= ntiles) break;
        PHASE(d0, d1, t3)
        if (t0 >= ntiles) break;
    }
#undef LOADT
#undef COMPUTE_STORE
#undef PHASE
}

extern "C" void kernel_launch(void* const* d_in, const int* in_sizes, int n_in,
                              void* d_out, int out_size, void* d_ws, size_t ws_size,
                              hipStream_t stream) {
    const float* X  = (const float*)d_in[0];
    const float* W0 = (const float*)d_in[1];
    const float* W1 = (const float*)d_in[2];
    const float* W2 = (const float*)d_in[3];
    float* Y = (float*)d_out;

    const int batch  = in_sizes[0] / 32;
    const int ntiles = batch / 16;               // 125,000

    int blocks = 1024;                           // 4 blocks/CU resident (no LDS, VGPR<=128)
    if (blocks * WAVES > ntiles) blocks = (ntiles + WAVES - 1) / WAVES;

    hipLaunchKernelGGL(mlp_kernel, dim3(blocks), dim3(256), 0, stream,
                       X, W0, W1, W2, Y, ntiles);
}

// Round 7
// 67.343 us; speedup vs baseline: 1.0917x; 1.0917x over previous
//
#include <hip/hip_runtime.h>

typedef float f32x4 __attribute__((ext_vector_type(4)));
typedef _Float16 f16x8 __attribute__((ext_vector_type(8)));
typedef _Float16 f16x4 __attribute__((ext_vector_type(4)));
typedef int i32x4 __attribute__((ext_vector_type(4)));
typedef int i32x2 __attribute__((ext_vector_type(2)));

#define WAVES 4

__device__ __forceinline__ f32x4 mfma16(f16x8 a, f16x8 b, f32x4 c) {
    return __builtin_amdgcn_mfma_f32_16x16x32_f16(a, b, c, 0, 0, 0);
}

// 8 consecutive k-elements (fp32) -> fp16 fragment, RNE
__device__ __forceinline__ f16x8 cvt8(f32x4 a, f32x4 b) {
    f16x8 h;
#pragma unroll
    for (int j = 0; j < 4; ++j) { h[j] = (_Float16)a[j]; h[j + 4] = (_Float16)b[j]; }
    return h;
}

// relu + pack one accumulator quad (4 f32) -> 2 dwords of fp16 pairs
__device__ __forceinline__ i32x2 relu_pk2(f32x4 a) {
    f16x4 v;
#pragma unroll
    for (int j = 0; j < 4; ++j) v[j] = (_Float16)fmaxf(a[j], 0.0f);
    return __builtin_bit_cast(i32x2, v);
}

// B-fragment = concat of two packed quads -- pure register move.
__device__ __forceinline__ f16x8 cat(i32x2 a, i32x2 b) {
    i32x4 v; v[0] = a[0]; v[1] = a[1]; v[2] = b[0]; v[3] = b[1];
    return __builtin_bit_cast(f16x8, v);
}

// Orientation: D[m=neuron][n=batch]. mfma_f32_16x16x32_f16 layouts (HW-verified R1-R6):
//   A: lane l supplies A[l&15][8*(l>>4)+j]
//   B: lane l supplies B[8*(l>>4)+j][l&15]
//   D: lane l holds   D[4*(l>>4)+r][l&15]
// Hidden-neuron permutation phi(32s+8g+j) = 16*(2s+(j>>2)) + 4g + (j&3) makes each
// lane's next-layer B-fragment its own packed accumulators (zero cross-lane traffic);
// W1/W2 columns are loaded phi-gathered (two contiguous f32x4 loads per fragment).
//
// Memory structure (this round): THREE pair-buffers (12 KB in flight per wave, 1.5x R5).
// To fit 128 VGPR / 4 blocks/CU, W0+W1 fragment tables live in a 12 KB per-block LDS
// table (built once + one __syncthreads). Per-tile LDS read base is laundered through
// empty asm volatile so LICM can't hoist the loop-invariant frags back into registers.
__global__ __launch_bounds__(256, 4) void mlp_kernel(
    const float* __restrict__ X, const float* __restrict__ W0,
    const float* __restrict__ W1, const float* __restrict__ W2,
    float* __restrict__ Y, int ntiles)
{
    // wtab entries: e = idx*64 + lane, 16B each.
    //   idx 0..3  : W0 fragment, t = idx
    //   idx 4..11 : W1 fragment, t = (idx-4)>>1, s = (idx-4)&1
    __shared__ __align__(16) _Float16 wtab[768 * 8];   // 12 KB

    const int tid  = threadIdx.x;
    const int wid  = tid >> 6;
    const int lane = tid & 63;
    const int b16  = lane & 15;
    const int g    = lane >> 4;

    // ---- build LDS fragment table (cooperative, 3 entries/thread) ----
    for (int e = tid; e < 768; e += 256) {
        const int le = e & 63, b16e = le & 15, ge = le >> 4;
        f16x8 fr;
        if (e < 256) {
            const int t = e >> 6;
            const float* p = W0 + (16 * t + b16e) * 32 + 8 * ge;      // unpermuted cols
            fr = cvt8(*(const f32x4*)p, *(const f32x4*)(p + 4));
        } else {
            const int idx = (e - 256) >> 6, t = idx >> 1, s = idx & 1;
            const float* p = W1 + (16 * t + b16e) * 64 + 32 * s + 4 * ge;  // phi-gathered
            fr = cvt8(*(const f32x4*)p, *(const f32x4*)(p + 16));
        }
        *(f16x8*)((char*)wtab + e * 16) = fr;
    }

    // ---- W2 fragments stay in registers (8 VGPR) ----
    f16x8 w2[2];
#pragma unroll
    for (int s = 0; s < 2; ++s) {
        const float* p = W2 + b16 * 64 + 32 * s + 4 * g;              // phi-gathered
        w2[s] = cvt8(*(const f32x4*)p, *(const f32x4*)(p + 16));
    }

    __syncthreads();

    const int xoff = b16 * 32 + 8 * g;    // float offset within a 16x32 input tile
    const int yoff = b16 * 16 + 4 * g;    // float offset within a 16x16 output tile

    const int npairs = (ntiles + 1) >> 1;
    const int gwid = blockIdx.x * WAVES + wid;
    const int G    = gridDim.x * WAVES;
    if (gwid >= npairs) return;           // after __syncthreads (barrier safety)

#define WFRAG(off, imm) (*(const f16x8*)((const char*)wtab + (off) + (imm)))

#define LOADP(d0, d1, d2, d3, p)                                                 \
    {                                                                            \
        const int pc = ((p) < npairs) ? (p) : gwid;  /* clamped, always valid */ \
        const float* xp_ = X + (size_t)(2 * pc) * 512 + xoff;                    \
        const size_t o1_ = (2 * pc + 1 < ntiles) ? 512 : 0;                      \
        d0 = *(const f32x4*)xp_;          d1 = *(const f32x4*)(xp_ + 4);         \
        d2 = *(const f32x4*)(xp_ + o1_);  d3 = *(const f32x4*)(xp_ + o1_ + 4);   \
    }

    // one 16-row tile: fp16 input fragment -> 16 outputs, nontemporal store
#define COMPUTE_STORE(xa, p, u)                                                  \
    {                                                                            \
        int o0_ = lane * 16;                                                     \
        asm volatile("" : "+v"(o0_));                /* defeat LICM */           \
        i32x2 pk[4];                                                             \
        _Pragma("unroll")                                                        \
        for (int t_ = 0; t_ < 4; ++t_) {                                         \
            f32x4 z = {0.f, 0.f, 0.f, 0.f};                                      \
            z = mfma16(WFRAG(o0_, t_ * 1024), xa, z);                            \
            pk[t_] = relu_pk2(z);                                                \
        }                                                                        \
        f32x4 c[4];                                                              \
        _Pragma("unroll")                                                        \
        for (int t_ = 0; t_ < 4; ++t_) c[t_] = (f32x4){0.f, 0.f, 0.f, 0.f};      \
        int o1_ = o0_;                                                           \
        asm volatile("" : "+v"(o1_) :: "memory");    /* stage reg pressure */    \
        const f16x8 f0 = cat(pk[0], pk[1]);                                      \
        _Pragma("unroll")                                                        \
        for (int t_ = 0; t_ < 4; ++t_)                                           \
            c[t_] = mfma16(WFRAG(o1_, 4096 + (2 * t_) * 1024), f0, c[t_]);       \
        int o2_ = o1_;                                                           \
        asm volatile("" : "+v"(o2_) :: "memory");                                \
        const f16x8 f1 = cat(pk[2], pk[3]);                                      \
        _Pragma("unroll")                                                        \
        for (int t_ = 0; t_ < 4; ++t_)                                           \
            c[t_] = mfma16(WFRAG(o2_, 4096 + (2 * t_ + 1) * 1024), f1, c[t_]);   \
        i32x2 qq[4];                                                             \
        _Pragma("unroll")                                                        \
        for (int t_ = 0; t_ < 4; ++t_) qq[t_] = relu_pk2(c[t_]);                 \
        f32x4 o = {0.f, 0.f, 0.f, 0.f};                                          \
        o = mfma16(w2[0], cat(qq[0], qq[1]), o);                                 \
        o = mfma16(w2[1], cat(qq[2], qq[3]), o);                                 \
        float* yp_ = Y + ((size_t)(2 * (p)) + (u)) * 256 + yoff;                 \
        __builtin_nontemporal_store(o, (f32x4*)yp_);                             \
    }

    // phase: consume pair buffer (pair p), refill it for p+3G, compute+store both tiles
#define PHASE(d0, d1, d2, d3, p)                                                 \
    {                                                                            \
        const f16x8 xa_ = cvt8(d0, d1);                                          \
        const f16x8 xb_ = cvt8(d2, d3);                                          \
        const int pn_ = (p) + 3 * G;                                             \
        LOADP(d0, d1, d2, d3, pn_)                                               \
        COMPUTE_STORE(xa_, p, 0)                                                 \
        COMPUTE_STORE(xb_, p, 1)                                                 \
        p = pn_;                                                                 \
    }

    int p0 = gwid, p1 = p0 + G, p2 = p1 + G;

    f32x4 a0, a1, a2, a3;   // pair buffer A
    f32x4 b0, b1, b2, b3;   // pair buffer B
    f32x4 c0, c1, c2, c3;   // pair buffer C
    LOADP(a0, a1, a2, a3, p0)
    LOADP(b0, b1, b2, b3, p1)
    LOADP(c0, c1, c2, c3, p2)

    while (true) {
        PHASE(a0, a1, a2, a3, p0)
        if (p1 >= npairs) break;
        PHASE(b0, b1, b2, b3, p1)
        if (p2 >= npairs) break;
        PHASE(c0, c1, c2, c3, p2)
        if (p0 >= npairs) break;
    }
#undef WFRAG
#undef LOADP
#undef COMPUTE_STORE
#undef PHASE
}

extern "C" void kernel_launch(void* const* d_in, const int* in_sizes, int n_in,
                              void* d_out, int out_size, void* d_ws, size_t ws_size,
                              hipStream_t stream) {
    const float* X  = (const float*)d_in[0];
    const float* W0 = (const float*)d_in[1];
    const float* W1 = (const float*)d_in[2];
    const float* W2 = (const float*)d_in[3];
    float* Y = (float*)d_out;

    const int batch  = in_sizes[0] / 32;
    const int ntiles = batch / 16;               // 125,000
    const int npairs = (ntiles + 1) >> 1;        // 62,500

    int blocks = 1024;                           // 4 blocks/CU resident (12KB LDS, VGPR<=128)
    if (blocks * WAVES > npairs) blocks = (npairs + WAVES - 1) / WAVES;

    hipLaunchKernelGGL(mlp_kernel, dim3(blocks), dim3(256), 0, stream,
                       X, W0, W1, W2, Y, ntiles);
}